// Round 7
// baseline (319.414 us; speedup 1.0000x reference)
//
#include <hip/hip_runtime.h>

typedef __bf16 bf16x8 __attribute__((ext_vector_type(8)));
typedef float f32x4 __attribute__((ext_vector_type(4)));
typedef unsigned short ushort8 __attribute__((ext_vector_type(8)));
typedef unsigned short u16x4 __attribute__((ext_vector_type(4)));

#define BATCH 8
#define SEQ 4096
#define DH 128
#define PSTR 40      // u16: 32 keys + 8 pad; rows 80 B (16B-aligned slots)
#define SC (0.08838834764831845f * 1.4426950408889634f)

__device__ __forceinline__ unsigned short f2bf(float x) {   // RNE
    unsigned int u = __builtin_bit_cast(unsigned int, x);
    u = (u + 0x7FFFu + ((u >> 16) & 1u)) >> 16;
    return (unsigned short)u;
}
__device__ __forceinline__ ushort8 cvt8(const float* __restrict__ p) {
    f32x4 a = *(const f32x4*)p;
    f32x4 b = *(const f32x4*)(p + 4);
    ushort8 r;
    r[0] = f2bf(a[0]); r[1] = f2bf(a[1]); r[2] = f2bf(a[2]); r[3] = f2bf(a[3]);
    r[4] = f2bf(b[0]); r[5] = f2bf(b[1]); r[6] = f2bf(b[2]); r[7] = f2bf(b[3]);
    return r;
}
__device__ __forceinline__ bf16x8 ldg8(const unsigned short* p) {
    return __builtin_bit_cast(bf16x8, *(const ushort8*)p);
}

// ---- fused prep: blocks [0,2048): K fp32->bf16 ; [2048,3072): V -> V^T bf16
#define KBLKS 2048
__global__ __launch_bounds__(256) void prep(const float* __restrict__ Kg,
                                            const float* __restrict__ Vg,
                                            unsigned short* __restrict__ Kbf,
                                            unsigned short* __restrict__ Vtg) {
    const int tid = threadIdx.x;
    if (blockIdx.x < KBLKS) {
        size_t i = ((size_t)blockIdx.x * 256 + tid) * 8;
        *(ushort8*)(Kbf + i) = cvt8(Kg + i);
        return;
    }
    // V transpose: tile = 128 keys x 32 d
    __shared__ float T[32 * 132];          // [d][k], pad 4
    const int vb = blockIdx.x - KBLKS;     // 0..1023
    const int b  = vb >> 7;                // batch
    const int t  = vb & 127;
    const int kt = t >> 2;                 // 0..31 (128-key tile)
    const int dt = t & 3;                  // 0..3  (32-d tile)
#pragma unroll
    for (int i = 0; i < 4; ++i) {
        int k  = (tid >> 3) + i * 32;      // 0..127
        int c4 = (tid & 7) * 4;
        f32x4 v = *(const f32x4*)(Vg + ((size_t)b * SEQ + kt * 128 + k) * DH + dt * 32 + c4);
#pragma unroll
        for (int j = 0; j < 4; ++j) T[(c4 + j) * 132 + k] = v[j];
    }
    __syncthreads();
    {
        int d = tid >> 3, ks = (tid & 7) * 16;
        unsigned short* dst = Vtg + ((size_t)b * DH + dt * 32 + d) * SEQ + kt * 128 + ks;
        *(ushort8*)(dst)     = cvt8(&T[d * 132 + ks]);
        *(ushort8*)(dst + 8) = cvt8(&T[d * 132 + ks + 8]);
    }
}

// ---- main: barrier-free, wave-independent 32q x 4096k jobs.
// S^T = K*Q^T (A=K-frags from global, B=Q in regs); m89 C/D: row=quad*4+reg, col=l16.
// P packed b64 to per-wave LDS; PV: A=P (LDS b128), B=V^T-frags from global.
template<int PREP>
__device__ __forceinline__ void attn_impl(
    const float* __restrict__ Qg, const float* __restrict__ Kg,
    const float* __restrict__ Vg,
    const unsigned short* __restrict__ Kbf, const unsigned short* __restrict__ Vtg,
    float* __restrict__ Og)
{
    __shared__ __align__(16) unsigned short Pls[2][32 * PSTR];   // 5120 B total

    const int tid  = threadIdx.x;
    const int wv   = tid >> 6;
    const int lane = tid & 63;
    const int l16  = lane & 15;
    const int quad = lane >> 4;

    const int b  = blockIdx.x & 7;          // batch == XCD slot (L2 residency)
    const int qt = blockIdx.x >> 3;         // 0..63
    const size_t qbase = (size_t)b * SEQ + (size_t)qt * 64 + wv * 32;

    // Q B-frags: B[k=d=quad*8+j][n=q=l16], 2 q-subtiles x 4 d-chunks
    bf16x8 qf[2][4];
#pragma unroll
    for (int s = 0; s < 2; ++s) {
        const float* qp = Qg + (qbase + s * 16 + l16) * DH + quad * 8;
#pragma unroll
        for (int c = 0; c < 4; ++c)
            qf[s][c] = __builtin_bit_cast(bf16x8, cvt8(qp + c * 32));
    }

    const f32x4 vzero = {0.f, 0.f, 0.f, 0.f};
    f32x4 oacc[2][8];
#pragma unroll
    for (int s = 0; s < 2; ++s)
#pragma unroll
        for (int d = 0; d < 8; ++d) oacc[s][d] = vzero;
    float lp[2] = {0.f, 0.f};               // per-lane denom partial at q=l16

    const unsigned short* Kb = Kbf + (size_t)b * SEQ * DH;
    const unsigned short* Vt = Vtg + (size_t)b * DH * SEQ;
    unsigned short* Pw = &Pls[wv][0];

    for (int kb = 0; kb < SEQ; kb += 32) {
        // ---- A-frags (K) direct from global bf16: rows kb+t*16+l16
        bf16x8 kf[2][4];
        bf16x8 vf[8];
        if (PREP) {
#pragma unroll
            for (int t = 0; t < 2; ++t) {
                const unsigned short* kp = Kb + (size_t)(kb + t * 16 + l16) * DH + quad * 8;
#pragma unroll
                for (int c = 0; c < 4; ++c) kf[t][c] = ldg8(kp + c * 32);
            }
#pragma unroll
            for (int d = 0; d < 8; ++d)
                vf[d] = ldg8(Vt + (size_t)(d * 16 + l16) * SEQ + kb + quad * 8);
        } else {
            // correct-but-slow fallback (ws too small): cvt K rows, scalar V columns
#pragma unroll
            for (int t = 0; t < 2; ++t) {
                const float* kp = Kg + ((size_t)b * SEQ + kb + t * 16 + l16) * DH + quad * 8;
#pragma unroll
                for (int c = 0; c < 4; ++c)
                    kf[t][c] = __builtin_bit_cast(bf16x8, cvt8(kp + c * 32));
            }
#pragma unroll
            for (int d = 0; d < 8; ++d) {
                ushort8 vv;
#pragma unroll
                for (int j = 0; j < 8; ++j)
                    vv[j] = f2bf(Vg[((size_t)b * SEQ + kb + quad * 8 + j) * DH + d * 16 + l16]);
                vf[d] = __builtin_bit_cast(bf16x8, vv);
            }
        }

        // ---- S^T = K*Q^T : D[row=key=quad*4+r][col=q=l16]
        f32x4 st[2][2] = {{vzero, vzero}, {vzero, vzero}};
#pragma unroll
        for (int c = 0; c < 4; ++c)
#pragma unroll
            for (int s = 0; s < 2; ++s) {
                st[s][0] = __builtin_amdgcn_mfma_f32_16x16x32_bf16(kf[0][c], qf[s][c], st[s][0], 0, 0, 0);
                st[s][1] = __builtin_amdgcn_mfma_f32_16x16x32_bf16(kf[1][c], qf[s][c], st[s][1], 0, 0, 0);
            }

        // ---- P = exp2(S*SC): 4 consecutive keys per lane -> packed b64 stores
#pragma unroll
        for (int s = 0; s < 2; ++s)
#pragma unroll
            for (int t = 0; t < 2; ++t) {
                u16x4 pk;
                float ps = 0.f;
#pragma unroll
                for (int r = 0; r < 4; ++r) {
                    float p = exp2f(st[s][t][r] * SC);
                    ps += p;
                    pk[r] = f2bf(p);
                }
                lp[s] += ps;
                *(u16x4*)(Pw + (s * 16 + l16) * PSTR + t * 16 + quad * 4) = pk;
            }
        asm volatile("s_waitcnt lgkmcnt(0)" ::: "memory");   // wave-local P fence

        // ---- O += P*V : A=P[q=l16][k=quad*8+j], B=V^T-frag
        bf16x8 pf0 = ldg8(Pw + (l16     ) * PSTR + quad * 8);
        bf16x8 pf1 = ldg8(Pw + (16 + l16) * PSTR + quad * 8);
#pragma unroll
        for (int d = 0; d < 8; ++d) {
            oacc[0][d] = __builtin_amdgcn_mfma_f32_16x16x32_bf16(pf0, vf[d], oacc[0][d], 0, 0, 0);
            oacc[1][d] = __builtin_amdgcn_mfma_f32_16x16x32_bf16(pf1, vf[d], oacc[1][d], 0, 0, 0);
        }
    }

    // ---- epilogue: l at q=l16 -> reduce over quads, shuffle to q=quad*4+r rows
#pragma unroll
    for (int s = 0; s < 2; ++s) {
        float L = lp[s];
        L += __shfl_xor(L, 16);
        L += __shfl_xor(L, 32);
        float* Ob = Og + (qbase + s * 16) * DH;
#pragma unroll
        for (int r = 0; r < 4; ++r) {
            float inv = 1.0f / __shfl(L, quad * 4 + r);
#pragma unroll
            for (int d = 0; d < 8; ++d)
                Ob[(quad * 4 + r) * DH + d * 16 + l16] = oacc[s][d][r] * inv;
        }
    }
}

__global__ __launch_bounds__(128, 2)
void attn_fwd(const float* __restrict__ Qg, const float* __restrict__ Kg,
              const float* __restrict__ Vg,
              const unsigned short* __restrict__ Kbf,
              const unsigned short* __restrict__ Vtg,
              float* __restrict__ Og, int prepped)
{
    if (prepped) attn_impl<1>(Qg, Kg, Vg, Kbf, Vtg, Og);
    else         attn_impl<0>(Qg, Kg, Vg, Kbf, Vtg, Og);
}

extern "C" void kernel_launch(void* const* d_in, const int* in_sizes, int n_in,
                              void* d_out, int out_size, void* d_ws, size_t ws_size,
                              hipStream_t stream) {
    const float* Q = (const float*)d_in[0];
    const float* K = (const float*)d_in[1];
    const float* V = (const float*)d_in[2];
    float* O = (float*)d_out;

    const size_t nelem = (size_t)BATCH * SEQ * DH;          // 4,194,304
    const bool prepped = (ws_size >= nelem * 4);            // 16.8 MB
    unsigned short* Kbf = (unsigned short*)d_ws;
    unsigned short* Vtg = Kbf + nelem;

    if (prepped)
        prep<<<dim3(KBLKS + BATCH * 128), 256, 0, stream>>>(K, V, Kbf, Vtg);
    attn_fwd<<<dim3(BATCH * (SEQ / 64)), 128, 0, stream>>>(Q, K, V, Kbf, Vtg, O,
                                                           prepped ? 1 : 0);
}